// Round 11
// baseline (232.261 us; speedup 1.0000x reference)
//
#include <hip/hip_runtime.h>
#include <hip/hip_bf16.h>
#include <math.h>

#define N_TS   19000
#define RPB    32         // rows per block (2 j-tiles of 16)
#define NBLKS  594        // 594*32 = 19008 >= 19000
#define T_DIM  168
#define T_PAD  192        // 6 * 32
#define U_DIM  256
#define NBLK   3
#define HOR    24

using bf16 = __hip_bfloat16;
typedef short v8s __attribute__((ext_vector_type(8)));   // 8 bf16 (MFMA A/B frag)
typedef float v4f __attribute__((ext_vector_type(4)));   // MFMA C/D frag

#define MFMA(a, b, c) __builtin_amdgcn_mfma_f32_16x16x32_bf16((a), (b), (c), 0, 0, 0)

// Raw barrier: drain LDS ops, leave global loads in flight.
#define BAR() do { asm volatile("s_waitcnt lgkmcnt(0)" ::: "memory"); \
                   __builtin_amdgcn_s_barrier(); } while (0)

__device__ __forceinline__ float softplus_f(float z) {
    return fmaxf(z, 0.0f) + __logf(1.0f + __expf(-fabsf(z)));
}
__device__ __forceinline__ unsigned pack2bf(float a, float b) {
    __hip_bfloat162 t = __float22bfloat162_rn(make_float2(a, b));
    return *(unsigned*)&t;
}
__device__ __forceinline__ short f2bf_s(float x) {
    bf16 h = __float2bfloat16(x); return *(short*)&h;
}
__device__ __forceinline__ v8s make_v8(float4 f0, float4 f1) {
    v8s r;
    r[0] = f2bf_s(f0.x); r[1] = f2bf_s(f0.y); r[2] = f2bf_s(f0.z); r[3] = f2bf_s(f0.w);
    r[4] = f2bf_s(f1.x); r[5] = f2bf_s(f1.y); r[6] = f2bf_s(f1.z); r[7] = f2bf_s(f1.w);
    return r;
}

// ---------------------------------------------------------------------------
// Weight prep (unchanged from R9/R10).
// ---------------------------------------------------------------------------
__global__ __launch_bounds__(256) void wprep(
    const float* __restrict__ Wl, const float* __restrict__ Wl1,
    const float* __restrict__ Wv, const float* __restrict__ bv,
    const float* __restrict__ Wo, const float* __restrict__ bo,
    const float* __restrict__ W20, const float* __restrict__ Wfc2,
    bf16* __restrict__ Wlb, bf16* __restrict__ Wl1b, bf16* __restrict__ Wvob,
    bf16* __restrict__ W20b, bf16* __restrict__ Wfc2b, float* __restrict__ bvo)
{
    const int blk = blockIdx.x, j = threadIdx.x;
    if (blk < 192) {
        const int b = blk / 64, n0 = (blk % 64) * 4;
        const float* wo0 = Wo + (size_t)(b * 256 + n0 + 0) * 256;
        const float* wo1 = Wo + (size_t)(b * 256 + n0 + 1) * 256;
        const float* wo2 = Wo + (size_t)(b * 256 + n0 + 2) * 256;
        const float* wo3 = Wo + (size_t)(b * 256 + n0 + 3) * 256;
        const float* Wv_b = Wv + (size_t)b * 65536;
        float a0 = 0.f, a1 = 0.f, a2 = 0.f, a3 = 0.f;
        #pragma unroll 4
        for (int t = 0; t < 256; ++t) {
            float v = Wv_b[(size_t)t * 256 + j];
            a0 = fmaf(wo0[t], v, a0); a1 = fmaf(wo1[t], v, a1);
            a2 = fmaf(wo2[t], v, a2); a3 = fmaf(wo3[t], v, a3);
        }
        Wvob[(size_t)(b * 256 + n0 + 0) * 256 + j] = __float2bfloat16(a0);
        Wvob[(size_t)(b * 256 + n0 + 1) * 256 + j] = __float2bfloat16(a1);
        Wvob[(size_t)(b * 256 + n0 + 2) * 256 + j] = __float2bfloat16(a2);
        Wvob[(size_t)(b * 256 + n0 + 3) * 256 + j] = __float2bfloat16(a3);

        __shared__ float4 red[256];
        const float bvv = bv[b * 256 + j];
        red[j] = make_float4(wo0[j] * bvv, wo1[j] * bvv, wo2[j] * bvv, wo3[j] * bvv);
        __syncthreads();
        for (int s = 128; s > 0; s >>= 1) {
            if (j < s) {
                float4 x0 = red[j], x1 = red[j + s];
                red[j] = make_float4(x0.x + x1.x, x0.y + x1.y, x0.z + x1.z, x0.w + x1.w);
            }
            __syncthreads();
        }
        if (j == 0) {
            float4 r0 = red[0];
            bvo[b * 256 + n0 + 0] = r0.x + bo[b * 256 + n0 + 0];
            bvo[b * 256 + n0 + 1] = r0.y + bo[b * 256 + n0 + 1];
            bvo[b * 256 + n0 + 2] = r0.z + bo[b * 256 + n0 + 2];
            bvo[b * 256 + n0 + 3] = r0.w + bo[b * 256 + n0 + 3];
        }
    } else if (blk < 960) {
        const int idx = blk - 192, b = idx >> 8, r = idx & 255;
        if (j < T_PAD)
            Wlb[(size_t)(b * 256 + r) * T_PAD + j] =
                __float2bfloat16(j < T_DIM ? Wl[(size_t)(b * 256 + r) * T_DIM + j] : 0.f);
    } else if (blk < 1728) {
        const int idx = blk - 960, b = idx >> 8, r = idx & 255;
        Wl1b[(size_t)(b * 256 + r) * 256 + j] =
            __float2bfloat16(Wl1[(size_t)(b * 256 + r) * 256 + j]);
    } else if (blk < 2304) {
        const int idx = blk - 1728, b = idx / T_PAD, r = idx % T_PAD;
        W20b[(size_t)(b * T_PAD + r) * 256 + j] =
            __float2bfloat16(r < T_DIM ? W20[(size_t)(b * T_DIM + r) * 256 + j] : 0.f);
    } else {
        const int r = blk - 2304;   // 0..31
        if (j < T_PAD)
            Wfc2b[r * T_PAD + j] =
                __float2bfloat16((r < HOR && j < T_DIM) ? Wfc2[r * T_DIM + j] : 0.f);
    }
}

// ---------------------------------------------------------------------------
// Weight loader. Layout dst[i*NKS + ks].
// ---------------------------------------------------------------------------
template<int NKS, int NI>
__device__ __forceinline__ void loadW(v8s (&dst)[16], const bf16* __restrict__ W,
                                      int ld, int rowA, int rowB, int kq)
{
    #pragma unroll
    for (int i = 0; i < NI; ++i) {
        const int r = (i == 0) ? rowA : rowB;
        #pragma unroll
        for (int ks = 0; ks < NKS; ++ks)
            dst[i * NKS + ks] = *(const v8s*)&W[(size_t)r * ld + ks * 32 + 8 * kq];
    }
}

// ---------------------------------------------------------------------------
// h-to-h phase: dst = act(src @ W^T (+bias)); wave w owns cols [32w,32w+32).
// src/dst are swizzled bf16 LDS tiles (stride 512 B, byte (2c)^((row&7)<<4)).
// ---------------------------------------------------------------------------
template<int NKS, bool SP, bool BIAS>
__device__ __forceinline__ void computeH(const v8s (&wreg)[16],
    const char* src, char* dst, const float* __restrict__ bias,
    int w, int r16, int kq, int swz)
{
    v4f acc[2][2] = {};
    #pragma unroll
    for (int ks = 0; ks < NKS; ++ks)
        #pragma unroll
        for (int j = 0; j < 2; ++j) {
            v8s bfr = *(const v8s*)(src + (16 * j + r16) * 512 + ((64 * ks + 16 * kq) ^ swz));
            acc[0][j] = MFMA(wreg[0 * NKS + ks], bfr, acc[0][j]);
            acc[1][j] = MFMA(wreg[1 * NKS + ks], bfr, acc[1][j]);
        }
    #pragma unroll
    for (int i = 0; i < 2; ++i) {
        const int c0 = 32 * w + 16 * i + 4 * kq;
        float4 bb = make_float4(0.f, 0.f, 0.f, 0.f);
        if (BIAS) bb = *(const float4*)&bias[c0];
        #pragma unroll
        for (int j = 0; j < 2; ++j) {
            float v0 = acc[i][j][0], v1 = acc[i][j][1], v2 = acc[i][j][2], v3 = acc[i][j][3];
            if (BIAS) { v0 += bb.x; v1 += bb.y; v2 += bb.z; v3 += bb.w; }
            if (SP) { v0 = softplus_f(v0); v1 = softplus_f(v1);
                      v2 = softplus_f(v2); v3 = softplus_f(v3); }
            *(uint2*)(dst + (16 * j + r16) * 512 + ((2 * c0) ^ swz)) =
                make_uint2(pack2bf(v0, v1), pack2bf(v2, v3));
        }
    }
}

// ---------------------------------------------------------------------------
// Persistent fused network. 594 blocks x 512 threads (8 waves), 32 rows/block.
// LDS 56 KB/block -> 2 blocks/CU co-resident = 4 waves/SIMD; two blocks per CU
// destagger phases (one block's MFMA overlaps the other's VALU/epilogue).
// No register weight double-buffer (R10: compiler couldn't hold it anyway);
// latency hiding is structural TLP. launch_bounds(512,4) caps VGPR at 128.
// ---------------------------------------------------------------------------
__global__ __launch_bounds__(512, 4) void fused_net(
    const bf16* __restrict__ Wlb, const bf16* __restrict__ Wl1b,
    const bf16* __restrict__ Wvob, const bf16* __restrict__ W20b,
    const bf16* __restrict__ Wfc2b, const float* __restrict__ bvo,
    const float* __restrict__ x, float* __restrict__ out)
{
    __shared__ __align__(16) bf16  hA[RPB * 256];   // 16 KB
    __shared__ __align__(16) bf16  hB[RPB * 256];   // 16 KB (doubles as hXb)
    __shared__ __align__(16) float hX[RPB * 192];   // 24 KB f32 residual

    const int tid  = threadIdx.x;
    const int lane = tid & 63, w = tid >> 6;        // 8 waves
    const int r16  = lane & 15, kq = lane >> 4;
    const int swz  = (r16 & 7) << 4;
    const int bm   = blockIdx.x * RPB;

    v8s wreg[16];

    // ---- stage x rows [bm, bm+32) into hX (f32) + hXb (bf16, in hB) ----
    for (int u = tid; u < RPB * 48; u += 512) {
        const int r = u / 48, q = u - r * 48;       // col quad q: cols 4q..4q+3
        const int gr = bm + r;
        float4 v = make_float4(0.f, 0.f, 0.f, 0.f);
        if (gr < N_TS && q < 42)
            v = *(const float4*)&x[(size_t)gr * T_DIM + 4 * q];
        const int sr = (r & 7) << 4;
        *(float4*)((char*)hX + r * 768 + ((16 * q) ^ sr)) = v;
        *(uint2*)((char*)hB + r * 512 + ((8 * q) ^ sr)) =
            make_uint2(pack2bf(v.x, v.y), pack2bf(v.z, v.w));
    }
    BAR();

    for (int b = 0; b < NBLK; ++b) {
        // ---- G1: hA = softplus(hXb @ Wl^T), K=192 ----
        loadW<6, 2>(wreg, Wlb + (size_t)b * 256 * T_PAD, T_PAD,
                    32 * w + r16, 32 * w + 16 + r16, kq);
        computeH<6, true, false>(wreg, (const char*)hB, (char*)hA, nullptr, w, r16, kq, swz);
        BAR();

        // ---- G2: hB = softplus(hA @ Wl1^T), K=256 ----
        loadW<8, 2>(wreg, Wl1b + (size_t)b * 65536, 256,
                    32 * w + r16, 32 * w + 16 + r16, kq);
        computeH<8, true, false>(wreg, (const char*)hA, (char*)hB, nullptr, w, r16, kq, swz);
        BAR();

        // ---- G3: hA = hB @ Wvo^T + bvo, K=256 ----
        loadW<8, 2>(wreg, Wvob + (size_t)b * 65536, 256,
                    32 * w + r16, 32 * w + 16 + r16, kq);
        computeH<8, false, true>(wreg, (const char*)hB, (char*)hA, bvo + b * 256, w, r16, kq, swz);
        BAR();

        // ---- G4: hX += hA @ W20^T (f32 RMW) + bf16 image -> hB (hXb) ----
        {
            const bf16* W4 = W20b + (size_t)b * T_PAD * 256;
            if (w < 4) loadW<8, 2>(wreg, W4, 256, 16 * (2 * w) + r16, 16 * (2 * w + 1) + r16, kq);
            else       loadW<8, 1>(wreg, W4, 256, 16 * (8 + w - 4) + r16, 0, kq);
            const int ti0 = (w < 4) ? 2 * w : 8 + (w - 4);
            v4f acc[2][2] = {};
            #pragma unroll
            for (int ks = 0; ks < 8; ++ks)
                #pragma unroll
                for (int j = 0; j < 2; ++j) {
                    v8s bfr = *(const v8s*)((const char*)hA + (16 * j + r16) * 512 +
                                            ((64 * ks + 16 * kq) ^ swz));
                    acc[0][j] = MFMA(wreg[ks], bfr, acc[0][j]);
                    if (w < 4) acc[1][j] = MFMA(wreg[8 + ks], bfr, acc[1][j]);
                }
            #pragma unroll
            for (int i = 0; i < 2; ++i) {
                if (i == 1 && w >= 4) continue;
                const int c0 = 16 * (ti0 + i) + 4 * kq;
                #pragma unroll
                for (int j = 0; j < 2; ++j) {
                    const int row = 16 * j + r16;
                    char* pX = (char*)hX + row * 768 + ((4 * c0) ^ swz);
                    float4 v = *(float4*)pX;
                    v.x += acc[i][j][0]; v.y += acc[i][j][1];
                    v.z += acc[i][j][2]; v.w += acc[i][j][3];
                    *(float4*)pX = v;
                    *(uint2*)((char*)hB + row * 512 + ((2 * c0) ^ swz)) =
                        make_uint2(pack2bf(v.x, v.y), pack2bf(v.z, v.w));
                }
            }
        }
        BAR();
    }

    // ---- fc2: out = hX @ Wfc2^T; 4 units (t=u&1, j=u>>1) on waves 0-3 ----
    if (w < 4) {
        const int t = w & 1, j = w >> 1;
        v4f acc = {};
        #pragma unroll
        for (int ks = 0; ks < 6; ++ks) {
            const char* base = (const char*)hX + (16 * j + r16) * 768;
            const int   u0   = 128 * ks + 32 * kq;
            float4 f0 = *(const float4*)(base + (u0 ^ swz));
            float4 f1 = *(const float4*)(base + ((u0 + 16) ^ swz));
            v8s xv = make_v8(f0, f1);
            v8s a  = *(const v8s*)&Wfc2b[(size_t)(16 * t + r16) * T_PAD + ks * 32 + 8 * kq];
            acc = MFMA(a, xv, acc);
        }
        const int grow = bm + 16 * j + r16;
        const int col  = 16 * t + 4 * kq;
        if (grow < N_TS && col < HOR)
            *(float4*)&out[(size_t)grow * HOR + col] =
                make_float4(acc[0], acc[1], acc[2], acc[3]);
    }
}

// ---------------------------------------------------------------------------
extern "C" void kernel_launch(void* const* d_in, const int* in_sizes, int n_in,
                              void* d_out, int out_size, void* d_ws, size_t ws_size,
                              hipStream_t stream) {
    const float* x    = (const float*)d_in[0];
    const float* Wl   = (const float*)d_in[1];
    const float* Wl1  = (const float*)d_in[2];
    const float* Wv   = (const float*)d_in[7];
    const float* bv   = (const float*)d_in[8];
    const float* Wo   = (const float*)d_in[9];
    const float* bo   = (const float*)d_in[10];
    const float* W20  = (const float*)d_in[11];
    const float* Wfc2 = (const float*)d_in[12];
    float* out = (float*)d_out;

    char* p = (char*)d_ws;
    auto carve = [&](size_t bytes) { char* q = p; p += (bytes + 255) & ~(size_t)255; return q; };
    bf16*  Wlb   = (bf16*)carve((size_t)NBLK * 256 * T_PAD * 2);
    bf16*  Wl1b  = (bf16*)carve((size_t)NBLK * 256 * 256 * 2);
    bf16*  Wvob  = (bf16*)carve((size_t)NBLK * 256 * 256 * 2);
    bf16*  W20b  = (bf16*)carve((size_t)NBLK * T_PAD * 256 * 2);
    bf16*  Wfc2b = (bf16*)carve((size_t)32 * T_PAD * 2);
    float* bvo   = (float*)carve((size_t)NBLK * 256 * 4);

    wprep<<<dim3(2336), dim3(256), 0, stream>>>(
        Wl, Wl1, Wv, bv, Wo, bo, W20, Wfc2, Wlb, Wl1b, Wvob, W20b, Wfc2b, bvo);
    fused_net<<<dim3(NBLKS), dim3(512), 0, stream>>>(
        Wlb, Wl1b, Wvob, W20b, Wfc2b, bvo, x, out);
}